// Round 6
// baseline (44.937 us; speedup 1.0000x reference)
//
#include <hip/hip_runtime.h>
#include <hip/hip_fp16.h>

#define DIN 1024
#define H_SZ 512
#define OUT_SZ 512
#define EPSF 1e-8f

typedef __attribute__((ext_vector_type(8))) short short8v;   // 8 bf16 = 4 VGPRs
typedef __attribute__((ext_vector_type(4))) float f32x4;
typedef _Float16 half2v __attribute__((ext_vector_type(2)));

// fp32 -> bf16 (RNE)
static __device__ inline unsigned short f2bf(float f) {
    unsigned u = __float_as_uint(f);
    u = u + 0x7FFFu + ((u >> 16) & 1u);
    return (unsigned short)(u >> 16);
}

// ---------------- prep: x->bf16, W1->bf16, Wd->relu fp16 (one pass, ~10MB traffic) ----------------
// 8 elems/thread. x: 131072 thr, W1: 65536, Wd: 32768 -> 229376 = 896 blocks x 256.
__global__ __launch_bounds__(256) void prep(const float* __restrict__ x,
                                            const float* __restrict__ W1,
                                            const float* __restrict__ Wd,
                                            unsigned short* __restrict__ xb,
                                            unsigned short* __restrict__ w1b,
                                            unsigned short* __restrict__ wh) {
    const int i = blockIdx.x * 256 + threadIdx.x;
    if (i < 131072) {
        const float4 a = *reinterpret_cast<const float4*>(&x[(size_t)i * 8]);
        const float4 b = *reinterpret_cast<const float4*>(&x[(size_t)i * 8 + 4]);
        short8v v;
        v[0] = (short)f2bf(a.x); v[1] = (short)f2bf(a.y); v[2] = (short)f2bf(a.z); v[3] = (short)f2bf(a.w);
        v[4] = (short)f2bf(b.x); v[5] = (short)f2bf(b.y); v[6] = (short)f2bf(b.z); v[7] = (short)f2bf(b.w);
        *reinterpret_cast<short8v*>(&xb[(size_t)i * 8]) = v;
    } else if (i < 196608) {
        const int j = i - 131072;
        const float4 a = *reinterpret_cast<const float4*>(&W1[(size_t)j * 8]);
        const float4 b = *reinterpret_cast<const float4*>(&W1[(size_t)j * 8 + 4]);
        short8v v;
        v[0] = (short)f2bf(a.x); v[1] = (short)f2bf(a.y); v[2] = (short)f2bf(a.z); v[3] = (short)f2bf(a.w);
        v[4] = (short)f2bf(b.x); v[5] = (short)f2bf(b.y); v[6] = (short)f2bf(b.z); v[7] = (short)f2bf(b.w);
        *reinterpret_cast<short8v*>(&w1b[(size_t)j * 8]) = v;
    } else {
        const int j = i - 196608;
        const float4 a = *reinterpret_cast<const float4*>(&Wd[(size_t)j * 8]);
        const float4 b = *reinterpret_cast<const float4*>(&Wd[(size_t)j * 8 + 4]);
        short8v v;   // +0 only for non-positive (no -0 bits: magic-sub safety)
        v[0] = (short)__half_as_ushort(__float2half(a.x > 0.f ? a.x : 0.f));
        v[1] = (short)__half_as_ushort(__float2half(a.y > 0.f ? a.y : 0.f));
        v[2] = (short)__half_as_ushort(__float2half(a.z > 0.f ? a.z : 0.f));
        v[3] = (short)__half_as_ushort(__float2half(a.w > 0.f ? a.w : 0.f));
        v[4] = (short)__half_as_ushort(__float2half(b.x > 0.f ? b.x : 0.f));
        v[5] = (short)__half_as_ushort(__float2half(b.y > 0.f ? b.y : 0.f));
        v[6] = (short)__half_as_ushort(__float2half(b.z > 0.f ? b.z : 0.f));
        v[7] = (short)__half_as_ushort(__float2half(b.w > 0.f ? b.w : 0.f));
        *reinterpret_cast<short8v*>(&wh[(size_t)j * 8]) = v;
    }
}

// ---------------- GEMM on pre-converted bf16: lean K-loop (2 loads, 2 ds_writes, 2 mfma) ----------
// Tile 32x32, BK=64, LDS double-buffer (1 barrier/iter), 256 thr (4 waves, 16x16 quadrants each).
__global__ __launch_bounds__(256, 4) void gemm_bf(const unsigned short* __restrict__ xb,
                                                  const unsigned short* __restrict__ w1b,
                                                  const float* __restrict__ b1,
                                                  unsigned short* __restrict__ hh) {
    __shared__ unsigned short As[2][32][72];   // stride 72 bf16 = 144B: 16B-aligned rows, padded banks
    __shared__ unsigned short Bs[2][32][72];
    const int t = threadIdx.x;
    const int b0 = blockIdx.x * 32;
    const int j0 = blockIdx.y * 32;
    const int w  = t >> 6;
    const int l  = t & 63;
    const int m0 = (w >> 1) * 16;
    const int n0 = (w & 1) * 16;
    const int lr = l & 15;
    const int lk = (l >> 4) * 8;
    const int ar = t >> 3;                 // 0..31
    const int ko = (t & 7) * 8;            // 0..56

    f32x4 acc = {0.f, 0.f, 0.f, 0.f};

    const unsigned short* arow = &xb[(size_t)(b0 + ar) * DIN + ko];
    const unsigned short* brow = &w1b[(size_t)(j0 + ar) * DIN + ko];
    short8v pa = *reinterpret_cast<const short8v*>(arow);
    short8v pb = *reinterpret_cast<const short8v*>(brow);

    for (int k0 = 0; k0 < DIN; k0 += 64) {
        const int buf = (k0 >> 6) & 1;
        *reinterpret_cast<short8v*>(&As[buf][ar][ko]) = pa;
        *reinterpret_cast<short8v*>(&Bs[buf][ar][ko]) = pb;
        __syncthreads();   // writes of buf visible; buf^1's last reads were 2 syncs back -> safe
        if (k0 + 64 < DIN) {
            pa = *reinterpret_cast<const short8v*>(arow + k0 + 64);
            pb = *reinterpret_cast<const short8v*>(brow + k0 + 64);
        }
        #pragma unroll
        for (int s = 0; s < 2; ++s) {
            const short8v af = *reinterpret_cast<const short8v*>(&As[buf][m0 + lr][s * 32 + lk]);
            const short8v bf = *reinterpret_cast<const short8v*>(&Bs[buf][n0 + lr][s * 32 + lk]);
            acc = __builtin_amdgcn_mfma_f32_16x16x32_bf16(af, bf, acc, 0, 0, 0);
        }
    }

    // C/D layout (m89-verified): col = lane&15, row = (lane>>4)*4 + reg
    const int col = j0 + n0 + lr;
    const float bias = b1[col];
    #pragma unroll
    for (int r = 0; r < 4; ++r) {
        const int m = b0 + m0 + (l >> 4) * 4 + r;
        hh[(size_t)m * H_SZ + col] =
            __half_as_ushort(__float2half(fmaxf(acc[r] + bias, 0.0f)));
    }
}

// ---------------- fallback GEMM (round-5 proven: converts fp32 in-loop, folds Wd prep) ----------
__global__ __launch_bounds__(256, 4) void gemm_mfma(const float* __restrict__ x,
                                                    const float* __restrict__ W1,
                                                    const float* __restrict__ b1,
                                                    const float* __restrict__ Wd,
                                                    unsigned short* __restrict__ hh,
                                                    unsigned short* __restrict__ wh) {
    __shared__ unsigned short As[2][2][32][40];
    __shared__ unsigned short Bs[2][2][32][40];
    const int t = threadIdx.x;
    const int b0 = blockIdx.x * 32;
    const int j0 = blockIdx.y * 32;
    {
        const int flat = blockIdx.y * 32 + blockIdx.x;
        const int i = flat * 512 + t * 2;
        const float2 v = *reinterpret_cast<const float2*>(&Wd[i]);
        const float a0 = v.x > 0.f ? v.x : 0.f;
        const float a1 = v.y > 0.f ? v.y : 0.f;
        const unsigned u = (unsigned)__half_as_ushort(__float2half(a0)) |
                           ((unsigned)__half_as_ushort(__float2half(a1)) << 16);
        reinterpret_cast<unsigned*>(wh)[i >> 1] = u;
    }
    const int w  = t >> 6;
    const int l  = t & 63;
    const int m0 = (w >> 1) * 16;
    const int n0 = (w & 1) * 16;
    const int lr = l & 15;
    const int lk = (l >> 4) * 8;
    const int ar = t >> 3;
    const int ak = (t & 7) * 8;
    const int kh = ak >> 5;
    const int ko = ak & 31;
    f32x4 acc = {0.f, 0.f, 0.f, 0.f};
    const float* xrow = &x[(size_t)(b0 + ar) * DIN + ak];
    const float* wrow = &W1[(size_t)(j0 + ar) * DIN + ak];
    float4 pa0 = *reinterpret_cast<const float4*>(xrow);
    float4 pa1 = *reinterpret_cast<const float4*>(xrow + 4);
    float4 pb0 = *reinterpret_cast<const float4*>(wrow);
    float4 pb1 = *reinterpret_cast<const float4*>(wrow + 4);
    for (int k0 = 0; k0 < DIN; k0 += 64) {
        const int buf = (k0 >> 6) & 1;
        short8v av, bv;
        av[0] = (short)f2bf(pa0.x); av[1] = (short)f2bf(pa0.y);
        av[2] = (short)f2bf(pa0.z); av[3] = (short)f2bf(pa0.w);
        av[4] = (short)f2bf(pa1.x); av[5] = (short)f2bf(pa1.y);
        av[6] = (short)f2bf(pa1.z); av[7] = (short)f2bf(pa1.w);
        bv[0] = (short)f2bf(pb0.x); bv[1] = (short)f2bf(pb0.y);
        bv[2] = (short)f2bf(pb0.z); bv[3] = (short)f2bf(pb0.w);
        bv[4] = (short)f2bf(pb1.x); bv[5] = (short)f2bf(pb1.y);
        bv[6] = (short)f2bf(pb1.z); bv[7] = (short)f2bf(pb1.w);
        *reinterpret_cast<short8v*>(&As[buf][kh][ar][ko]) = av;
        *reinterpret_cast<short8v*>(&Bs[buf][kh][ar][ko]) = bv;
        __syncthreads();
        if (k0 + 64 < DIN) {
            pa0 = *reinterpret_cast<const float4*>(xrow + k0 + 64);
            pa1 = *reinterpret_cast<const float4*>(xrow + k0 + 68);
            pb0 = *reinterpret_cast<const float4*>(wrow + k0 + 64);
            pb1 = *reinterpret_cast<const float4*>(wrow + k0 + 68);
        }
        #pragma unroll
        for (int s = 0; s < 2; ++s) {
            const short8v af = *reinterpret_cast<const short8v*>(&As[buf][s][m0 + lr][lk]);
            const short8v bf = *reinterpret_cast<const short8v*>(&Bs[buf][s][n0 + lr][lk]);
            acc = __builtin_amdgcn_mfma_f32_16x16x32_bf16(af, bf, acc, 0, 0, 0);
        }
    }
    const int col = j0 + n0 + lr;
    const float bias = b1[col];
    #pragma unroll
    for (int r = 0; r < 4; ++r) {
        const int m = b0 + m0 + (l >> 4) * 4 + r;
        hh[(size_t)m * H_SZ + col] =
            __half_as_ushort(__float2half(fmaxf(acc[r] + bias, 0.0f)));
    }
}

// ---------------- Canberra: dist = 512 - 2*sum(min(h,w')/(h+w')),  sim = 1/dist ----------------
// Forced VOP3P via inline asm: exactly 6 packed ops per 2 terms (+1 v_sub_u32 magic seed).
// Numerics identical to rounds 3/5 (passed at 1.5e-5).
static __device__ inline void canb2(unsigned hu, unsigned wu, unsigned& a, unsigned two) {
    unsigned mn, sm, tt, y;
    asm("v_pk_min_f16 %0, %1, %2" : "=v"(mn) : "v"(hu), "v"(wu));
    asm("v_pk_add_f16 %0, %1, %2" : "=v"(sm) : "v"(hu), "v"(wu));
    y = 0x77847784u - sm;                           // v_sub_u32, literal in src0
    asm("v_pk_fma_f16 %0, %1, %2, %3 neg_lo:[1,0,0] neg_hi:[1,0,0]"
        : "=v"(tt) : "v"(sm), "v"(y), "v"(two));    // tt = 2 - sm*y
    asm("v_pk_mul_f16 %0, %1, %2" : "=v"(y) : "v"(y), "v"(tt));
    asm("v_pk_fma_f16 %0, %1, %2, %0" : "+v"(a) : "v"(mn), "v"(y));
}

// Block: 512 thr, out-tile 32b x 32o, k-split 4 (128 k each), 4b x 2o register tile.
// All LDS reads b128; stride 260 uints -> broadcast/2-way banks (free).
__global__ __launch_bounds__(512, 4) void canberra4(const unsigned short* __restrict__ hh,
                                                    const unsigned short* __restrict__ wh,
                                                    float* __restrict__ out) {
    __shared__ unsigned hs[32][260];
    __shared__ unsigned ws_[32][260];
    const int t = threadIdx.x;
    const int b0 = blockIdx.x * 32;
    const int o0 = blockIdx.y * 32;
    const unsigned* hu = reinterpret_cast<const unsigned*>(hh);
    const unsigned* wu = reinterpret_cast<const unsigned*>(wh);

    #pragma unroll
    for (int r = 0; r < 4; ++r) {
        const int s = t + r * 512;
        const int row = s >> 6;
        const int c16 = s & 63;
        *reinterpret_cast<uint4*>(&hs[row][c16 * 4]) =
            *reinterpret_cast<const uint4*>(&hu[(size_t)(b0 + row) * 256 + c16 * 4]);
        *reinterpret_cast<uint4*>(&ws_[row][c16 * 4]) =
            *reinterpret_cast<const uint4*>(&wu[(size_t)(o0 + row) * 256 + c16 * 4]);
    }
    __syncthreads();

    const int ks = t >> 7;
    const int ts = t & 127;
    const int bi = ts >> 4;
    const int oj = ts & 15;
    const unsigned two = 0x40004000u;   // {2.0h, 2.0h}

    unsigned acc[4][2] = {};

    const int base = ks * 64;
    #pragma unroll 2
    for (int g = 0; g < 16; ++g) {
        const int col = base + g * 4;
        uint4 hv[4], wv[2];
        #pragma unroll
        for (int c = 0; c < 4; ++c)
            hv[c] = *reinterpret_cast<const uint4*>(&hs[bi + 8 * c][col]);
        #pragma unroll
        for (int d = 0; d < 2; ++d)
            wv[d] = *reinterpret_cast<const uint4*>(&ws_[oj + 16 * d][col]);
        #pragma unroll
        for (int c = 0; c < 4; ++c) {
            #pragma unroll
            for (int d = 0; d < 2; ++d) {
                canb2(hv[c].x, wv[d].x, acc[c][d], two);
                canb2(hv[c].y, wv[d].y, acc[c][d], two);
                canb2(hv[c].z, wv[d].z, acc[c][d], two);
                canb2(hv[c].w, wv[d].w, acc[c][d], two);
            }
        }
    }

    float p[8];
    #pragma unroll
    for (int c = 0; c < 4; ++c)
        #pragma unroll
        for (int d = 0; d < 2; ++d) {
            const half2v av = __builtin_bit_cast(half2v, acc[c][d]);
            p[c * 2 + d] = (float)av.x + (float)av.y;
        }

    __syncthreads();
    float* red = reinterpret_cast<float*>(&hs[0][0]);
    if (ks > 0) {
        float* rp = &red[((size_t)(ks - 1) * 128 + ts) * 8];
        #pragma unroll
        for (int i = 0; i < 8; ++i) rp[i] = p[i];
    }
    __syncthreads();
    if (ks == 0) {
        #pragma unroll
        for (int q = 0; q < 3; ++q) {
            const float* rp = &red[((size_t)q * 128 + ts) * 8];
            #pragma unroll
            for (int i = 0; i < 8; ++i) p[i] += rp[i];
        }
        #pragma unroll
        for (int c = 0; c < 4; ++c) {
            #pragma unroll
            for (int d = 0; d < 2; ++d) {
                float dd = 512.0f - 2.0f * p[c * 2 + d] + EPSF;
                dd = fminf(fmaxf(dd, EPSF), 1000000.0f);
                out[(size_t)(b0 + bi + 8 * c) * OUT_SZ + o0 + oj + 16 * d] = 1.0f / dd;
            }
        }
    }
}

extern "C" void kernel_launch(void* const* d_in, const int* in_sizes, int n_in,
                              void* d_out, int out_size, void* d_ws, size_t ws_size,
                              hipStream_t stream) {
    const float* x  = (const float*)d_in[0];
    const float* W1 = (const float*)d_in[1];
    const float* b1 = (const float*)d_in[2];
    const float* Wd = (const float*)d_in[3];
    float* out = (float*)d_out;

    // ws layout: hh @0 (1MB), wh @1MB (0.5MB), xb @1.5MB (2MB), w1b @3.5MB (1MB)
    unsigned short* hh = (unsigned short*)d_ws;
    unsigned short* wh = (unsigned short*)((char*)d_ws + (1u << 20) / 2 * 2);
    wh = (unsigned short*)((char*)d_ws + (1u << 20));
    if (ws_size >= ((size_t)9 << 19)) {   // 4.5 MB
        unsigned short* xb  = (unsigned short*)((char*)d_ws + 3 * (1u << 19));   // +1.5MB
        unsigned short* w1b = (unsigned short*)((char*)d_ws + 7 * (1u << 19));   // +3.5MB
        prep<<<896, 256, 0, stream>>>(x, W1, Wd, xb, w1b, wh);
        gemm_bf<<<dim3(32, 16), 256, 0, stream>>>(xb, w1b, b1, hh);
    } else {
        gemm_mfma<<<dim3(32, 16), 256, 0, stream>>>(x, W1, b1, Wd, hh, wh);
    }
    canberra4<<<dim3(32, 16), 512, 0, stream>>>(hh, wh, out);
}